// Round 1
// baseline (131.931 us; speedup 1.0000x reference)
//
#include <hip/hip_runtime.h>
#include <hip/hip_bf16.h>

// Problem constants (from reference): DE=200, DR=200, IN=400, NUM_BASES=4.
// Output = embeddings[unseen_index] : 200 floats. Only edges with
// edge_dst == unseen_index contribute (~8 of 400000 expected).

#define DE 200
#define IN_DIM 400
#define ICHUNK 50          // IN_DIM / 8 i-chunks
#define NCHUNK 8
#define MAXJ 64            // edge-slot blocks in grid.y (loop-strided beyond)

// workspace layout:
//   [0]      int   count
//   [256]    float acc[200]
//   [4096]   int   match list
#define WS_ACC_OFF   64    // in floats (256 bytes)
#define WS_LIST_OFF  1024  // in ints   (4096 bytes)

__global__ void filter_k(const int* __restrict__ edge_dst,
                         const int* __restrict__ unseen,
                         int n_edges, int* __restrict__ ws_count,
                         int* __restrict__ ws_list, int max_list) {
    const int u = unseen[0];
    for (int e = blockIdx.x * blockDim.x + threadIdx.x; e < n_edges;
         e += gridDim.x * blockDim.x) {
        if (edge_dst[e] == u) {
            int pos = atomicAdd(ws_count, 1);
            if (pos < max_list) ws_list[pos] = e;
        }
    }
}

__global__ void compute_k(const float* __restrict__ Eemb,
                          const float* __restrict__ Remb,
                          const float* __restrict__ basis,
                          const float* __restrict__ att,
                          const int* __restrict__ node_id,
                          const int* __restrict__ edge_src,
                          const int* __restrict__ edge_type,
                          const int* __restrict__ rel_index,
                          const int* __restrict__ ws_count,
                          const int* __restrict__ ws_list,
                          float* __restrict__ acc, int max_list) {
    int cnt = ws_count[0];
    if (cnt > max_list) cnt = max_list;
    const int c = blockIdx.x;          // i-chunk
    const int base = c * ICHUNK;
    const int t = threadIdx.x;
    __shared__ float s_xj[ICHUNK];
    float m = 0.f;
    bool any = false;

    for (int j = blockIdx.y; j < cnt; j += gridDim.y) {
        const int e   = ws_list[j];
        const int src = edge_src[e];
        const int typ = edge_type[e];
        const int ri  = rel_index[e];
        __syncthreads();               // protect s_xj from prior-iter readers
        if (t < ICHUNK) {
            const int i = base + t;
            s_xj[t] = (i < DE) ? Eemb[(size_t)node_id[src] * DE + i]
                               : Remb[(size_t)ri * DE + (i - DE)];
        }
        __syncthreads();
        if (t < DE) {
            const float a0 = att[typ * 4 + 0];
            const float a1 = att[typ * 4 + 1];
            const float a2 = att[typ * 4 + 2];
            const float a3 = att[typ * 4 + 3];
            float h0 = 0.f, h1 = 0.f, h2 = 0.f, h3 = 0.f;
            // basis[b][i][o] at (b*IN_DIM + i)*DE + o ; b-stride = 80000
            #pragma unroll 5
            for (int ii = 0; ii < ICHUNK; ++ii) {
                const float xv = s_xj[ii];
                const int off = (base + ii) * DE + t;
                h0 += xv * basis[off];
                h1 += xv * basis[off + 80000];
                h2 += xv * basis[off + 160000];
                h3 += xv * basis[off + 240000];
            }
            m += a0 * h0 + a1 * h1 + a2 * h2 + a3 * h3;
            any = true;
        }
    }
    if (any) atomicAdd(&acc[t], m);
}

__global__ void finalize_k(const int* __restrict__ ws_count,
                           const float* __restrict__ acc,
                           float* __restrict__ out) {
    const int t = threadIdx.x;
    if (t < DE) {
        int c = ws_count[0];
        if (c < 1) c = 1;
        out[t] = acc[t] / (float)c;
    }
}

extern "C" void kernel_launch(void* const* d_in, const int* in_sizes, int n_in,
                              void* d_out, int out_size, void* d_ws, size_t ws_size,
                              hipStream_t stream) {
    const float* Eemb  = (const float*)d_in[0];
    const float* Remb  = (const float*)d_in[1];
    const float* basis = (const float*)d_in[2];
    const float* att   = (const float*)d_in[3];
    const int* node_id  = (const int*)d_in[4];
    const int* edge_src = (const int*)d_in[5];
    const int* edge_dst = (const int*)d_in[6];
    const int* edge_typ = (const int*)d_in[7];
    const int* rel_idx  = (const int*)d_in[8];
    const int* unseen   = (const int*)d_in[9];
    float* out = (float*)d_out;

    const int n_edges = in_sizes[6];

    int* ws_count = (int*)d_ws;
    float* acc    = (float*)d_ws + WS_ACC_OFF;
    int* ws_list  = (int*)d_ws + WS_LIST_OFF;
    long avail = (long)(ws_size / 4) - WS_LIST_OFF;
    int max_list = avail > 8192 ? 8192 : (avail > 0 ? (int)avail : 0);

    // zero count + accumulator (d_ws is poisoned to 0xAA before every launch)
    hipMemsetAsync(d_ws, 0, 4096, stream);

    int fblocks = (n_edges + 255) / 256;
    filter_k<<<fblocks, 256, 0, stream>>>(edge_dst, unseen, n_edges,
                                          ws_count, ws_list, max_list);

    dim3 cgrid(NCHUNK, MAXJ);
    compute_k<<<cgrid, 256, 0, stream>>>(Eemb, Remb, basis, att, node_id,
                                         edge_src, edge_typ, rel_idx,
                                         ws_count, ws_list, acc, max_list);

    finalize_k<<<1, 256, 0, stream>>>(ws_count, acc, out);
}